// Round 3
// baseline (223.328 us; speedup 1.0000x reference)
//
#include <hip/hip_runtime.h>
#include <hip/hip_bf16.h>
#include <math.h>

// Problem constants
#define B_ 64
#define L_ 256
#define H_ 1024
#define P_ 64
#define A_ 512
#define T_ 8
#define NSTEP 36

typedef __attribute__((ext_vector_type(8))) __bf16 bf16x8;
typedef __attribute__((ext_vector_type(4))) float f32x4;

__device__ __forceinline__ float bf2f(ushort u) {
  union { unsigned int i; float f; } v; v.i = ((unsigned int)u) << 16; return v.f;
}
__device__ __forceinline__ ushort f2bf_rne(float f) {
  union { float f; unsigned int i; } v; v.f = f;
  unsigned int r = v.i + 0x7FFFu + ((v.i >> 16) & 1u);  // RNE
  return (ushort)(r >> 16);
}
__device__ __forceinline__ unsigned int pack2_rne(float a, float b) {
  return (unsigned int)f2bf_rne(a) | ((unsigned int)f2bf_rne(b) << 16);
}

template <bool BF16>
__device__ __forceinline__ float ld1(const void* p, size_t i) {
  if (BF16) return bf2f(((const ushort*)p)[i]);
  return ((const float*)p)[i];
}
template <bool BF16>
__device__ __forceinline__ float4 ld4(const void* p, size_t i) {
  if (BF16) {
    ushort4 u = *(const ushort4*)((const ushort*)p + i);
    return (float4){bf2f(u.x), bf2f(u.y), bf2f(u.z), bf2f(u.w)};
  }
  return *(const float4*)((const float*)p + i);
}

// ---------------------------------------------------------------------------
// Kernel P: merged build_wts (blocks 0..575) + entity_features (576..639).
// ---------------------------------------------------------------------------
template <bool BF16>
__global__ __launch_bounds__(256) void prep_k(
    const void* __restrict__ wpos, ushort* __restrict__ WTs,
    const void* __restrict__ wh, const int* __restrict__ e1e,
    const int* __restrict__ e2e, const void* __restrict__ temb,
    float* __restrict__ EF) {
  if (blockIdx.x < 576) {
    __shared__ ushort tile[32][33];
    const int s  = blockIdx.x >> 4;   // 0..35 (k-step)
    const int at = blockIdx.x & 15;   // 0..15 (n tile of 32)
    const int tx = threadIdx.x & 31;
    const int ty = threadIdx.x >> 5;  // 0..7
#pragma unroll
    for (int i = 0; i < 4; ++i) {
      size_t idx = (size_t)(s * 32 + ty + i * 8) * A_ + at * 32 + tx;
      ushort u;
      if (BF16) u = ((const ushort*)wpos)[idx];
      else u = f2bf_rne(((const float*)wpos)[idx]);
      tile[ty + i * 8][tx] = u;
    }
    __syncthreads();
#pragma unroll
    for (int i = 0; i < 4; ++i) {
      WTs[(size_t)s * (A_ * 32) + (size_t)(at * 32 + ty + i * 8) * 32 + tx] =
          tile[tx][ty + i * 8];
    }
  } else {
    const int b = blockIdx.x - 576;
    const int tid = threadIdx.x;
    __shared__ float eh1[1024];
    __shared__ float eh2[1024];
    __shared__ float part[256][16];
    __shared__ float scores[16];
    __shared__ float alpha[16];

    const size_t o1 = ((size_t)b * L_ + e1e[b]) * H_;
    const size_t o2 = ((size_t)b * L_ + e2e[b]) * H_;
    for (int h = tid; h < 1024; h += 256) {
      eh1[h] = ld1<BF16>(wh, o1 + h);
      eh2[h] = ld1<BF16>(wh, o2 + h);
    }
    __syncthreads();

    float p[16];
#pragma unroll
    for (int t = 0; t < 16; ++t) p[t] = 0.f;
    for (int h = tid; h < 1024; h += 256) {
      float a1 = eh1[h], a2 = eh2[h];
#pragma unroll
      for (int t = 0; t < 8; ++t) {
        float c = ld1<BF16>(temb, t * 1024 + h);
        p[t] += a1 * c;
        p[8 + t] += a2 * c;
      }
    }
#pragma unroll
    for (int t = 0; t < 16; ++t) part[tid][t] = p[t];
    __syncthreads();
    if (tid < 16) {
      float s = 0.f;
      for (int i = 0; i < 256; ++i) s += part[i][tid];
      scores[tid] = s;
    }
    __syncthreads();
    if (tid < 2) {
      const int base = tid * 8;
      float mx = scores[base];
      for (int t = 1; t < 8; ++t) mx = fmaxf(mx, scores[base + t]);
      float sum = 0.f;
      float e[8];
      for (int t = 0; t < 8; ++t) { e[t] = __expf(scores[base + t] - mx); sum += e[t]; }
      float inv = 1.f / sum;
      for (int t = 0; t < 8; ++t) alpha[base + t] = e[t] * inv;
    }
    __syncthreads();

    float* efb = EF + (size_t)b * 4096;
    for (int h = tid; h < 1024; h += 256) {
      float l1 = 0.f, l2 = 0.f;
#pragma unroll
      for (int t = 0; t < 8; ++t) {
        float c = ld1<BF16>(temb, t * 1024 + h);
        l1 += alpha[t] * c;
        l2 += alpha[8 + t] * c;
      }
      efb[h] = eh1[h];
      efb[1024 + h] = l1;
      efb[2048 + h] = eh2[h];
      efb[3072 + h] = l2;
    }
  }
}

// ---------------------------------------------------------------------------
// Kernel E2: dense_ent partials = EF[64,4096] @ W_ent[4096,512], k-split 32.
// grid 256 = kb(32) x nb(4) x mh(2). part [32][64][512] fp32, deterministic.
// (unroll-4 reverted: R2 regression suspect)
// ---------------------------------------------------------------------------
template <bool BF16>
__global__ __launch_bounds__(256) void ent_gemm(const float* __restrict__ EF,
                                                const void* __restrict__ went,
                                                float* __restrict__ part) {
  const int mh = blockIdx.x & 1;
  const int nb = (blockIdx.x >> 1) & 3;
  const int kb = blockIdx.x >> 3;
  const int tid = threadIdx.x;
  __shared__ float efs[32][128];

  const int k0 = kb * 128;
  {
    const int kq = (tid & 31) * 4;
    for (int m = tid >> 5; m < 32; m += 8) {
      *(float4*)&efs[m][kq] = *(const float4*)&EF[(size_t)(mh * 32 + m) * 4096 + k0 + kq];
    }
  }
  __syncthreads();

  const int n0 = nb * 128 + (tid & 31) * 4;
  const int mg = (tid >> 5) * 4;
  float acc[4][4];
#pragma unroll
  for (int i = 0; i < 4; ++i)
#pragma unroll
    for (int j = 0; j < 4; ++j) acc[i][j] = 0.f;

  for (int k = 0; k < 128; ++k) {
    float4 w = ld4<BF16>(went, (size_t)(k0 + k) * A_ + n0);
#pragma unroll
    for (int i = 0; i < 4; ++i) {
      float e = efs[mg + i][k];
      acc[i][0] += e * w.x;
      acc[i][1] += e * w.y;
      acc[i][2] += e * w.z;
      acc[i][3] += e * w.w;
    }
  }
#pragma unroll
  for (int i = 0; i < 4; ++i) {
    *(float4*)&part[((size_t)kb * 64 + mh * 32 + mg + i) * A_ + n0] =
        (float4){acc[i][0], acc[i][1], acc[i][2], acc[i][3]};
  }
}

// ---------------------------------------------------------------------------
// Kernel E3: dense_ent[64][512] = sum over 32 k-chunks of part. grid 128.
// ---------------------------------------------------------------------------
__global__ __launch_bounds__(256) void ent_reduce(const float* __restrict__ part,
                                                  float* __restrict__ dense_ent) {
  const int idx = blockIdx.x * 256 + threadIdx.x;
  float s = 0.f;
#pragma unroll
  for (int kb = 0; kb < 32; ++kb) s += part[(size_t)kb * 32768 + idx];
  dense_ent[idx] = s;
}

// ---------------------------------------------------------------------------
// Kernel 4: fused MFMA GEMM  u = tanh(pos_features @ W_pos + ent) -> vu = u @ v
// BM=128, BN=128, BK=32. grid 512 -> 2 blocks/CU. Waves 2m x 2n, tile 64x64.
// R3 change: 4 LDS buffers + 4 register prefetch sets. Every global load now
// has ~2 MFMA-steps (~800+ cyc) in flight before its s_waitcnt at the LDS
// store, and barriers drop 36 -> 18 (one per 2 steps). Race check: every
// store(buf)->compute(buf) and compute(buf)->overwrite(buf) pair is separated
// by a __syncthreads. XOR chunk swizzle unchanged (verified conflict-free, R2).
// s_setprio(1) around MFMA cluster (waves come from independent blocks at
// unaligned phases -> scheduler has roles to arbitrate).
// ---------------------------------------------------------------------------
template <bool BF16>
__global__ __launch_bounds__(256, 2) void fused_gemm_vu(
    const void* __restrict__ wh, const void* __restrict__ pe1,
    const void* __restrict__ pe2, const ushort* __restrict__ WTs,
    const float* __restrict__ dense_ent, const void* __restrict__ vvec,
    float* __restrict__ vu_part) {
  __shared__ __align__(16) ushort Abuf[4][128 * 32];  // 8 KB each
  __shared__ __align__(16) ushort Bbuf[4][128 * 32];  // 8 KB each  (total 64 KB)
  __shared__ float vu_s[4][128];

  const int tid = threadIdx.x;
  const int pid = blockIdx.x;
  const int wid = (pid & 7) * 64 + (pid >> 3);  // XCD-contiguous, bijective (512%8==0)
  const int nb = wid & 3;           // 0..3 (n tile of 128)
  const int mb = wid >> 2;          // 0..127
  const int rbase = mb * 128;
  const int wave = tid >> 6;
  const int lane = tid & 63;
  const int quad = lane >> 4;
  const int col = lane & 15;
  const int wr = wave >> 1;         // m half (64 rows)
  const int wc = wave & 1;          // n half (64 cols)

  // Fragment LDS offsets (ushort units): row*32 + (chunk^((row>>1)&3))*8
  int aoff[4], boff[4];
#pragma unroll
  for (int mf = 0; mf < 4; ++mf) {
    const int ra = wr * 64 + mf * 16 + col;
    aoff[mf] = ra * 32 + ((quad ^ ((ra >> 1) & 3)) << 3);
    const int rb = wc * 64 + mf * 16 + col;
    boff[mf] = rb * 32 + ((quad ^ ((rb >> 1) & 3)) << 3);
  }

  // B staging: row = tid>>1, 32B half (chunks 2*(tid&1), +1)
  const int brow = tid >> 1;
  const int bc0 = (tid & 1) * 2;
  const int sB0 = brow * 32 + ((bc0 ^ ((brow >> 1) & 3)) << 3);  // pair at sB0^8
  const size_t bsrc_off = (size_t)(nb * 128 + brow) * 32 + (size_t)(tid & 1) * 16;

  // A staging (fp32 path): two passes, row_p = p*64 + (tid>>2), chunk q=tid&3
  const int ar0 = tid >> 2, aq = tid & 3;
  const int ar1 = 64 + ar0;
  const int sA0 = ar0 * 32 + ((aq ^ ((ar0 >> 1) & 3)) << 3);
  const int sA1 = ar1 * 32 + ((aq ^ ((ar1 >> 1) & 3)) << 3);

  f32x4 acc[4][4];
#pragma unroll
  for (int i = 0; i < 4; ++i)
#pragma unroll
    for (int j = 0; j < 4; ++j) acc[i][j] = (f32x4){0.f, 0.f, 0.f, 0.f};

  // Prefetch register set (static names only; no dynamic indexing).
  struct Set {
    float4 f0a, f0b, f1a, f1b;  // fp32 A
    uint4 u0, u1;               // bf16 A
    uint4 b0, b1;               // B
  };
  Set sx, sy, sz, sw;

  auto issue = [&](Set& S, int s) {
    const void* src; int ld, k0;
    if (s < 32)      { src = wh;  ld = H_; k0 = s * 32; }
    else if (s < 34) { src = pe1; ld = P_; k0 = (s - 32) * 32; }
    else             { src = pe2; ld = P_; k0 = (s - 34) * 32; }
    if (BF16) {
      const ushort* p = (const ushort*)src + (size_t)(rbase + brow) * ld + k0 + (tid & 1) * 16;
      S.u0 = *(const uint4*)p;
      S.u1 = *(const uint4*)(p + 8);
    } else {
      const float* p0 = (const float*)src + (size_t)(rbase + ar0) * ld + k0 + aq * 8;
      S.f0a = *(const float4*)p0;
      S.f0b = *(const float4*)(p0 + 4);
      const float* p1 = (const float*)src + (size_t)(rbase + ar1) * ld + k0 + aq * 8;
      S.f1a = *(const float4*)p1;
      S.f1b = *(const float4*)(p1 + 4);
    }
    const ushort* bs = WTs + (size_t)s * (A_ * 32) + bsrc_off;
    S.b0 = *(const uint4*)bs;
    S.b1 = *(const uint4*)(bs + 8);
  };
  auto store = [&](const Set& S, int buf) {
    if (BF16) {
      *(uint4*)&Abuf[buf][sB0] = S.u0;
      *(uint4*)&Abuf[buf][sB0 ^ 8] = S.u1;
    } else {
      uint4 u0 = {pack2_rne(S.f0a.x, S.f0a.y), pack2_rne(S.f0a.z, S.f0a.w),
                  pack2_rne(S.f0b.x, S.f0b.y), pack2_rne(S.f0b.z, S.f0b.w)};
      *(uint4*)&Abuf[buf][sA0] = u0;
      uint4 u1 = {pack2_rne(S.f1a.x, S.f1a.y), pack2_rne(S.f1a.z, S.f1a.w),
                  pack2_rne(S.f1b.x, S.f1b.y), pack2_rne(S.f1b.z, S.f1b.w)};
      *(uint4*)&Abuf[buf][sA1] = u1;
    }
    *(uint4*)&Bbuf[buf][sB0] = S.b0;
    *(uint4*)&Bbuf[buf][sB0 ^ 8] = S.b1;
  };
  auto compute = [&](int buf) {
    bf16x8 af[4], bfr[4];
#pragma unroll
    for (int mf = 0; mf < 4; ++mf) af[mf] = *(const bf16x8*)&Abuf[buf][aoff[mf]];
#pragma unroll
    for (int nf = 0; nf < 4; ++nf) bfr[nf] = *(const bf16x8*)&Bbuf[buf][boff[nf]];
    __builtin_amdgcn_s_setprio(1);
#pragma unroll
    for (int mf = 0; mf < 4; ++mf)
#pragma unroll
      for (int nf = 0; nf < 4; ++nf)
        acc[mf][nf] =
            __builtin_amdgcn_mfma_f32_16x16x32_bf16(af[mf], bfr[nf], acc[mf][nf], 0, 0, 0);
    __builtin_amdgcn_s_setprio(0);
  };

  // Prologue: 4 loads in flight; steps 0,1 staged to buffers 0,1.
  issue(sx, 0); issue(sy, 1); issue(sz, 2); issue(sw, 3);
  store(sx, 0); store(sy, 1);
  __syncthreads();

  for (int s = 0; s < NSTEP; s += 4) {
    // first half: compute steps s, s+1 (buf0, buf1); land s+2, s+3 (buf2, buf3)
    if (s + 4 < NSTEP) issue(sx, s + 4);
    compute(0);
    store(sz, 2);
    if (s + 5 < NSTEP) issue(sy, s + 5);
    compute(1);
    store(sw, 3);
    __syncthreads();
    // second half: compute steps s+2, s+3 (buf2, buf3); land s+4, s+5 (buf0, buf1)
    if (s + 6 < NSTEP) issue(sz, s + 6);
    compute(2);
    if (s + 4 < NSTEP) store(sx, 0);
    if (s + 7 < NSTEP) issue(sw, s + 7);
    compute(3);
    if (s + 5 < NSTEP) store(sy, 1);
    __syncthreads();
  }

  // Epilogue: C/D layout col=lane&15 (n), row=quad*4+reg (m). side = nb>>1.
  float vv[4];
#pragma unroll
  for (int nf = 0; nf < 4; ++nf)
    vv[nf] = ld1<BF16>(vvec, nb * 128 + wc * 64 + nf * 16 + col);

#pragma unroll
  for (int mf = 0; mf < 4; ++mf) {
    const int row0 = wr * 64 + mf * 16 + quad * 4;
    const int r0 = rbase + row0;
    const int bidx = r0 >> 8;
    const int l0 = r0 & 255;
    const float* ebase = dense_ent + bidx * A_ + 2 * l0 + (nb >> 1);
    float e0 = ebase[0], e1 = ebase[2], e2 = ebase[4], e3 = ebase[6];
    float s0 = 0.f, s1 = 0.f, s2 = 0.f, s3 = 0.f;
#pragma unroll
    for (int nf = 0; nf < 4; ++nf) {
      float vn = vv[nf];
      s0 += tanhf(acc[mf][nf][0] + e0) * vn;
      s1 += tanhf(acc[mf][nf][1] + e1) * vn;
      s2 += tanhf(acc[mf][nf][2] + e2) * vn;
      s3 += tanhf(acc[mf][nf][3] + e3) * vn;
    }
    s0 += __shfl_xor(s0, 1); s0 += __shfl_xor(s0, 2); s0 += __shfl_xor(s0, 4); s0 += __shfl_xor(s0, 8);
    s1 += __shfl_xor(s1, 1); s1 += __shfl_xor(s1, 2); s1 += __shfl_xor(s1, 4); s1 += __shfl_xor(s1, 8);
    s2 += __shfl_xor(s2, 1); s2 += __shfl_xor(s2, 2); s2 += __shfl_xor(s2, 4); s2 += __shfl_xor(s2, 8);
    s3 += __shfl_xor(s3, 1); s3 += __shfl_xor(s3, 2); s3 += __shfl_xor(s3, 4); s3 += __shfl_xor(s3, 8);
    if (col == 0) {
      vu_s[wave][row0 + 0] = s0;
      vu_s[wave][row0 + 1] = s1;
      vu_s[wave][row0 + 2] = s2;
      vu_s[wave][row0 + 3] = s3;
    }
  }
  __syncthreads();
  if (tid < 128) {
    const int wrr = tid >> 6;  // rows 0-63: waves 0,1; rows 64-127: waves 2,3
    float s = vu_s[wrr * 2][tid] + vu_s[wrr * 2 + 1][tid];
    vu_part[(size_t)nb * (B_ * L_) + rbase + tid] = s;
  }
}

// ---------------------------------------------------------------------------
// Kernel 5: per-b softmax over L, then z[b,h] = sum_l alpha[l] * wh[b,l,h]
// grid 256 = b*4 + hq. Sums the four n-partials of vu. 8-deep unroll.
// ---------------------------------------------------------------------------
template <bool BF16>
__global__ __launch_bounds__(256) void softmax_z(const void* __restrict__ wh,
                                                 const float* __restrict__ vu_part,
                                                 void* __restrict__ out) {
  const int b = blockIdx.x >> 2;
  const int hq = blockIdx.x & 3;
  const int tid = threadIdx.x;
  __shared__ float alpha[256];
  __shared__ float red[256];

  float x = 0.f;
#pragma unroll
  for (int p = 0; p < 4; ++p) x += vu_part[(size_t)p * (B_ * L_) + b * L_ + tid];
  red[tid] = x;
  __syncthreads();
  for (int s = 128; s > 0; s >>= 1) {
    if (tid < s) red[tid] = fmaxf(red[tid], red[tid + s]);
    __syncthreads();
  }
  float m = red[0];
  __syncthreads();
  float e = __expf(x - m);
  red[tid] = e;
  __syncthreads();
  for (int s = 128; s > 0; s >>= 1) {
    if (tid < s) red[tid] += red[tid + s];
    __syncthreads();
  }
  alpha[tid] = e / red[0];
  __syncthreads();

  const int h = hq * 256 + tid;
  const size_t base = (size_t)b * L_ * H_ + h;
  float a0 = 0.f, a1 = 0.f, a2 = 0.f, a3 = 0.f;
  float a4 = 0.f, a5 = 0.f, a6 = 0.f, a7 = 0.f;
  for (int l = 0; l < 256; l += 8) {
    a0 += alpha[l + 0] * ld1<BF16>(wh, base + (size_t)(l + 0) * H_);
    a1 += alpha[l + 1] * ld1<BF16>(wh, base + (size_t)(l + 1) * H_);
    a2 += alpha[l + 2] * ld1<BF16>(wh, base + (size_t)(l + 2) * H_);
    a3 += alpha[l + 3] * ld1<BF16>(wh, base + (size_t)(l + 3) * H_);
    a4 += alpha[l + 4] * ld1<BF16>(wh, base + (size_t)(l + 4) * H_);
    a5 += alpha[l + 5] * ld1<BF16>(wh, base + (size_t)(l + 5) * H_);
    a6 += alpha[l + 6] * ld1<BF16>(wh, base + (size_t)(l + 6) * H_);
    a7 += alpha[l + 7] * ld1<BF16>(wh, base + (size_t)(l + 7) * H_);
  }
  float z = ((a0 + a1) + (a2 + a3)) + ((a4 + a5) + (a6 + a7));
  if (BF16) ((ushort*)out)[b * H_ + h] = f2bf_rne(z);
  else ((float*)out)[b * H_ + h] = z;
}

// ---------------------------------------------------------------------------
extern "C" void kernel_launch(void* const* d_in, const int* in_sizes, int n_in,
                              void* d_out, int out_size, void* d_ws, size_t ws_size,
                              hipStream_t stream) {
  const void* wh   = d_in[0];
  const void* pe1  = d_in[1];
  const void* pe2  = d_in[2];
  const int*  e1e  = (const int*)d_in[3];
  const int*  e2e  = (const int*)d_in[4];
  const void* temb = d_in[5];
  const void* wpos = d_in[6];
  const void* went = d_in[7];
  const void* vvec = d_in[8];

  const bool bf16 = (in_sizes[0] == (int)(B_ * L_ * H_ * 2));

  char* ws = (char*)d_ws;
  ushort* WTs      = (ushort*)ws;                  // 1,179,648 B
  float* dense_ent = (float*)(ws + 1179648);       // 131,072 B
  float* vu_part   = (float*)(ws + 1310720);       // 262,144 B (aliases EF head;
  float* EF        = (float*)(ws + 1310720);       //  EF dead before fused runs)
  float* part      = (float*)(ws + 2359296);       // 4,194,304 B

  if (bf16) {
    prep_k<true ><<<dim3(640), dim3(256), 0, stream>>>(wpos, WTs, wh, e1e, e2e, temb, EF);
    ent_gemm<true ><<<dim3(256), dim3(256), 0, stream>>>(EF, went, part);
    ent_reduce<<<dim3(128), dim3(256), 0, stream>>>(part, dense_ent);
    fused_gemm_vu<true ><<<dim3(512), dim3(256), 0, stream>>>(wh, pe1, pe2, WTs, dense_ent, vvec, vu_part);
    softmax_z<true ><<<dim3(256), dim3(256), 0, stream>>>(wh, vu_part, d_out);
  } else {
    prep_k<false><<<dim3(640), dim3(256), 0, stream>>>(wpos, WTs, wh, e1e, e2e, temb, EF);
    ent_gemm<false><<<dim3(256), dim3(256), 0, stream>>>(EF, went, part);
    ent_reduce<<<dim3(128), dim3(256), 0, stream>>>(part, dense_ent);
    fused_gemm_vu<false><<<dim3(512), dim3(256), 0, stream>>>(wh, pe1, pe2, WTs, dense_ent, vvec, vu_part);
    softmax_z<false><<<dim3(256), dim3(256), 0, stream>>>(wh, vu_part, d_out);
  }
}

// Round 5
// 189.375 us; speedup vs baseline: 1.1793x; 1.1793x over previous
//
#include <hip/hip_runtime.h>
#include <hip/hip_bf16.h>
#include <math.h>

// Problem constants
#define B_ 64
#define L_ 256
#define H_ 1024
#define P_ 64
#define A_ 512
#define T_ 8
#define NSTEP 36

typedef __attribute__((ext_vector_type(8))) __bf16 bf16x8;
typedef __attribute__((ext_vector_type(4))) float f32x4;

__device__ __forceinline__ float bf2f(ushort u) {
  union { unsigned int i; float f; } v; v.i = ((unsigned int)u) << 16; return v.f;
}
__device__ __forceinline__ ushort f2bf_rne(float f) {
  union { float f; unsigned int i; } v; v.f = f;
  unsigned int r = v.i + 0x7FFFu + ((v.i >> 16) & 1u);  // RNE
  return (ushort)(r >> 16);
}
__device__ __forceinline__ unsigned int pack2_rne(float a, float b) {
  return (unsigned int)f2bf_rne(a) | ((unsigned int)f2bf_rne(b) << 16);
}

template <bool BF16>
__device__ __forceinline__ float ld1(const void* p, size_t i) {
  if (BF16) return bf2f(((const ushort*)p)[i]);
  return ((const float*)p)[i];
}
template <bool BF16>
__device__ __forceinline__ float4 ld4(const void* p, size_t i) {
  if (BF16) {
    ushort4 u = *(const ushort4*)((const ushort*)p + i);
    return (float4){bf2f(u.x), bf2f(u.y), bf2f(u.z), bf2f(u.w)};
  }
  return *(const float4*)((const float*)p + i);
}

// ---------------------------------------------------------------------------
// Kernel P: merged build_wts (blocks 0..575) + entity_features (576..639).
// ---------------------------------------------------------------------------
template <bool BF16>
__global__ __launch_bounds__(256) void prep_k(
    const void* __restrict__ wpos, ushort* __restrict__ WTs,
    const void* __restrict__ wh, const int* __restrict__ e1e,
    const int* __restrict__ e2e, const void* __restrict__ temb,
    float* __restrict__ EF) {
  if (blockIdx.x < 576) {
    __shared__ ushort tile[32][33];
    const int s  = blockIdx.x >> 4;   // 0..35 (k-step)
    const int at = blockIdx.x & 15;   // 0..15 (n tile of 32)
    const int tx = threadIdx.x & 31;
    const int ty = threadIdx.x >> 5;  // 0..7
#pragma unroll
    for (int i = 0; i < 4; ++i) {
      size_t idx = (size_t)(s * 32 + ty + i * 8) * A_ + at * 32 + tx;
      ushort u;
      if (BF16) u = ((const ushort*)wpos)[idx];
      else u = f2bf_rne(((const float*)wpos)[idx]);
      tile[ty + i * 8][tx] = u;
    }
    __syncthreads();
#pragma unroll
    for (int i = 0; i < 4; ++i) {
      WTs[(size_t)s * (A_ * 32) + (size_t)(at * 32 + ty + i * 8) * 32 + tx] =
          tile[tx][ty + i * 8];
    }
  } else {
    const int b = blockIdx.x - 576;
    const int tid = threadIdx.x;
    __shared__ float eh1[1024];
    __shared__ float eh2[1024];
    __shared__ float part[256][16];
    __shared__ float scores[16];
    __shared__ float alpha[16];

    const size_t o1 = ((size_t)b * L_ + e1e[b]) * H_;
    const size_t o2 = ((size_t)b * L_ + e2e[b]) * H_;
    for (int h = tid; h < 1024; h += 256) {
      eh1[h] = ld1<BF16>(wh, o1 + h);
      eh2[h] = ld1<BF16>(wh, o2 + h);
    }
    __syncthreads();

    float p[16];
#pragma unroll
    for (int t = 0; t < 16; ++t) p[t] = 0.f;
    for (int h = tid; h < 1024; h += 256) {
      float a1 = eh1[h], a2 = eh2[h];
#pragma unroll
      for (int t = 0; t < 8; ++t) {
        float c = ld1<BF16>(temb, t * 1024 + h);
        p[t] += a1 * c;
        p[8 + t] += a2 * c;
      }
    }
#pragma unroll
    for (int t = 0; t < 16; ++t) part[tid][t] = p[t];
    __syncthreads();
    if (tid < 16) {
      float s = 0.f;
      for (int i = 0; i < 256; ++i) s += part[i][tid];
      scores[tid] = s;
    }
    __syncthreads();
    if (tid < 2) {
      const int base = tid * 8;
      float mx = scores[base];
      for (int t = 1; t < 8; ++t) mx = fmaxf(mx, scores[base + t]);
      float sum = 0.f;
      float e[8];
      for (int t = 0; t < 8; ++t) { e[t] = __expf(scores[base + t] - mx); sum += e[t]; }
      float inv = 1.f / sum;
      for (int t = 0; t < 8; ++t) alpha[base + t] = e[t] * inv;
    }
    __syncthreads();

    float* efb = EF + (size_t)b * 4096;
    for (int h = tid; h < 1024; h += 256) {
      float l1 = 0.f, l2 = 0.f;
#pragma unroll
      for (int t = 0; t < 8; ++t) {
        float c = ld1<BF16>(temb, t * 1024 + h);
        l1 += alpha[t] * c;
        l2 += alpha[8 + t] * c;
      }
      efb[h] = eh1[h];
      efb[1024 + h] = l1;
      efb[2048 + h] = eh2[h];
      efb[3072 + h] = l2;
    }
  }
}

// ---------------------------------------------------------------------------
// Kernel E2: dense_ent partials = EF[64,4096] @ W_ent[4096,512], k-split 32.
// grid 256 = kb(32) x nb(4) x mh(2). part [32][64][512] fp32, deterministic.
// ---------------------------------------------------------------------------
template <bool BF16>
__global__ __launch_bounds__(256) void ent_gemm(const float* __restrict__ EF,
                                                const void* __restrict__ went,
                                                float* __restrict__ part) {
  const int mh = blockIdx.x & 1;
  const int nb = (blockIdx.x >> 1) & 3;
  const int kb = blockIdx.x >> 3;
  const int tid = threadIdx.x;
  __shared__ float efs[32][128];

  const int k0 = kb * 128;
  {
    const int kq = (tid & 31) * 4;
    for (int m = tid >> 5; m < 32; m += 8) {
      *(float4*)&efs[m][kq] = *(const float4*)&EF[(size_t)(mh * 32 + m) * 4096 + k0 + kq];
    }
  }
  __syncthreads();

  const int n0 = nb * 128 + (tid & 31) * 4;
  const int mg = (tid >> 5) * 4;
  float acc[4][4];
#pragma unroll
  for (int i = 0; i < 4; ++i)
#pragma unroll
    for (int j = 0; j < 4; ++j) acc[i][j] = 0.f;

  for (int k = 0; k < 128; ++k) {
    float4 w = ld4<BF16>(went, (size_t)(k0 + k) * A_ + n0);
#pragma unroll
    for (int i = 0; i < 4; ++i) {
      float e = efs[mg + i][k];
      acc[i][0] += e * w.x;
      acc[i][1] += e * w.y;
      acc[i][2] += e * w.z;
      acc[i][3] += e * w.w;
    }
  }
#pragma unroll
  for (int i = 0; i < 4; ++i) {
    *(float4*)&part[((size_t)kb * 64 + mh * 32 + mg + i) * A_ + n0] =
        (float4){acc[i][0], acc[i][1], acc[i][2], acc[i][3]};
  }
}

// ---------------------------------------------------------------------------
// Kernel E3: dense_ent[64][512] = sum over 32 k-chunks of part. grid 128.
// ---------------------------------------------------------------------------
__global__ __launch_bounds__(256) void ent_reduce(const float* __restrict__ part,
                                                  float* __restrict__ dense_ent) {
  const int idx = blockIdx.x * 256 + threadIdx.x;
  float s = 0.f;
#pragma unroll
  for (int kb = 0; kb < 32; ++kb) s += part[(size_t)kb * 32768 + idx];
  dense_ent[idx] = s;
}

// ---------------------------------------------------------------------------
// Kernel 4: fused MFMA GEMM  u = tanh(pos_features @ W_pos + ent) -> vu = u @ v
// R4 (resubmit; R4 bench was an infra failure): combine the two proven wins:
//   - R2's conflict-free XOR chunk swizzle + X/Y 2-deep register prefetch
//     (VGPR 92, WRITE_SIZE 256B — no spills)
//   - R1's 4 blocks/CU occupancy (BM=64 -> grid 1024)
// BM=64, BN=128, BK=32. grid 1024 -> 4 blocks/CU, LDS 24 KB/block.
// 4 waves as 2m x 2n; wave tile 32x64 (2x4 frags, 8 MFMA/step).
// launch_bounds(256,4): 4 blocks/CU needs VGPR<=128 (we need ~80; no spill).
// XCD-contiguous swizzle: 1024%8==0, bijective; nb-siblings share an XCD L2.
// dense_ent_r[b,l,a] = dense_ent[b, 2l + (a>=256)]; side == nb>>1 (uniform).
// ---------------------------------------------------------------------------
template <bool BF16>
__global__ __launch_bounds__(256, 4) void fused_gemm_vu(
    const void* __restrict__ wh, const void* __restrict__ pe1,
    const void* __restrict__ pe2, const ushort* __restrict__ WTs,
    const float* __restrict__ dense_ent, const void* __restrict__ vvec,
    float* __restrict__ vu_part) {
  __shared__ __align__(16) ushort Abuf[2][64 * 32];   // 4 KB each
  __shared__ __align__(16) ushort Bbuf[2][128 * 32];  // 8 KB each (total 24 KB)
  __shared__ float vu_s[4][64];

  const int tid = threadIdx.x;
  const int pid = blockIdx.x;
  const int wid = (pid & 7) * 128 + (pid >> 3);  // XCD-contiguous, bijective (1024%8==0)
  const int nb = wid & 3;            // 0..3 (n tile of 128)
  const int mb = wid >> 2;           // 0..255
  const int rbase = mb * 64;
  const int wave = tid >> 6;
  const int lane = tid & 63;
  const int quad = lane >> 4;
  const int col = lane & 15;
  const int wr = wave >> 1;          // m half (32 rows)
  const int wc = wave & 1;           // n half (64 cols)

  // Fragment LDS offsets (ushort units): row*32 + (chunk^((row>>1)&3))*8
  // (same formula as R2 — measured 0 bank conflicts)
  int aoff[2], boff[4];
#pragma unroll
  for (int mf = 0; mf < 2; ++mf) {
    const int ra = wr * 32 + mf * 16 + col;
    aoff[mf] = ra * 32 + ((quad ^ ((ra >> 1) & 3)) << 3);
  }
#pragma unroll
  for (int nf = 0; nf < 4; ++nf) {
    const int rb = wc * 64 + nf * 16 + col;
    boff[nf] = rb * 32 + ((quad ^ ((rb >> 1) & 3)) << 3);
  }

  // B staging: row = tid>>1, 32B half (chunks 2*(tid&1), +1) — as R2
  const int brow = tid >> 1;
  const int bc0 = (tid & 1) * 2;
  const int sB0 = brow * 32 + ((bc0 ^ ((brow >> 1) & 3)) << 3);  // pair at sB0^8
  const size_t bsrc_off = (size_t)(nb * 128 + brow) * 32 + (size_t)(tid & 1) * 16;

  // A staging: 64 rows, one 16B chunk per thread: row = tid>>2, chunk = tid&3
  const int ar0 = tid >> 2, aq = tid & 3;
  const int sA0 = ar0 * 32 + ((aq ^ ((ar0 >> 1) & 3)) << 3);

  f32x4 acc[2][4];
#pragma unroll
  for (int i = 0; i < 2; ++i)
#pragma unroll
    for (int j = 0; j < 4; ++j) acc[i][j] = (f32x4){0.f, 0.f, 0.f, 0.f};

  // Two prefetch register sets (X, Y) — static names, no structs, no spills.
  float4 fXa, fXb; uint4 uX; uint4 bX0, bX1;
  float4 fYa, fYb; uint4 uY; uint4 bY0, bY1;

  auto ISSUE_X = [&](int s) {
    const void* src; int ld, k0;
    if (s < 32)      { src = wh;  ld = H_; k0 = s * 32; }
    else if (s < 34) { src = pe1; ld = P_; k0 = (s - 32) * 32; }
    else             { src = pe2; ld = P_; k0 = (s - 34) * 32; }
    if (BF16) {
      uX = *(const uint4*)((const ushort*)src + (size_t)(rbase + ar0) * ld + k0 + aq * 8);
    } else {
      const float* p0 = (const float*)src + (size_t)(rbase + ar0) * ld + k0 + aq * 8;
      fXa = *(const float4*)p0;
      fXb = *(const float4*)(p0 + 4);
    }
    const ushort* bs = WTs + (size_t)s * (A_ * 32) + bsrc_off;
    bX0 = *(const uint4*)bs;
    bX1 = *(const uint4*)(bs + 8);
  };
  auto ISSUE_Y = [&](int s) {
    const void* src; int ld, k0;
    if (s < 32)      { src = wh;  ld = H_; k0 = s * 32; }
    else if (s < 34) { src = pe1; ld = P_; k0 = (s - 32) * 32; }
    else             { src = pe2; ld = P_; k0 = (s - 34) * 32; }
    if (BF16) {
      uY = *(const uint4*)((const ushort*)src + (size_t)(rbase + ar0) * ld + k0 + aq * 8);
    } else {
      const float* p0 = (const float*)src + (size_t)(rbase + ar0) * ld + k0 + aq * 8;
      fYa = *(const float4*)p0;
      fYb = *(const float4*)(p0 + 4);
    }
    const ushort* bs = WTs + (size_t)s * (A_ * 32) + bsrc_off;
    bY0 = *(const uint4*)bs;
    bY1 = *(const uint4*)(bs + 8);
  };
  auto STORE_X = [&](int buf) {
    if (BF16) {
      *(uint4*)&Abuf[buf][sA0] = uX;
    } else {
      uint4 u0 = {pack2_rne(fXa.x, fXa.y), pack2_rne(fXa.z, fXa.w),
                  pack2_rne(fXb.x, fXb.y), pack2_rne(fXb.z, fXb.w)};
      *(uint4*)&Abuf[buf][sA0] = u0;
    }
    *(uint4*)&Bbuf[buf][sB0] = bX0;
    *(uint4*)&Bbuf[buf][sB0 ^ 8] = bX1;
  };
  auto STORE_Y = [&](int buf) {
    if (BF16) {
      *(uint4*)&Abuf[buf][sA0] = uY;
    } else {
      uint4 u0 = {pack2_rne(fYa.x, fYa.y), pack2_rne(fYa.z, fYa.w),
                  pack2_rne(fYb.x, fYb.y), pack2_rne(fYb.z, fYb.w)};
      *(uint4*)&Abuf[buf][sA0] = u0;
    }
    *(uint4*)&Bbuf[buf][sB0] = bY0;
    *(uint4*)&Bbuf[buf][sB0 ^ 8] = bY1;
  };
  auto COMPUTE = [&](int buf) {
    bf16x8 af[2], bfr[4];
#pragma unroll
    for (int mf = 0; mf < 2; ++mf) af[mf] = *(const bf16x8*)&Abuf[buf][aoff[mf]];
#pragma unroll
    for (int nf = 0; nf < 4; ++nf) bfr[nf] = *(const bf16x8*)&Bbuf[buf][boff[nf]];
#pragma unroll
    for (int mf = 0; mf < 2; ++mf)
#pragma unroll
      for (int nf = 0; nf < 4; ++nf)
        acc[mf][nf] =
            __builtin_amdgcn_mfma_f32_16x16x32_bf16(af[mf], bfr[nf], acc[mf][nf], 0, 0, 0);
  };

  // Prologue: L0 -> X (store now), L1 -> Y (stored mid-iteration).
  ISSUE_X(0);
  ISSUE_Y(1);
  STORE_X(0);
  __syncthreads();

  for (int s = 0; s < NSTEP; s += 2) {
    if (s + 2 < NSTEP) ISSUE_X(s + 2);   // ~1 full step in flight before wait
    COMPUTE(0);                           // step s
    STORE_Y(1);                           // L(s+1) -> LDS[1]
    __syncthreads();
    if (s + 3 < NSTEP) ISSUE_Y(s + 3);
    COMPUTE(1);                           // step s+1
    if (s + 2 < NSTEP) {
      STORE_X(0);                         // L(s+2) -> LDS[0]
      __syncthreads();
    }
  }

  // Epilogue: C/D layout col=lane&15 (n), row=quad*4+reg (m). side = nb>>1.
  float vv[4];
#pragma unroll
  for (int nf = 0; nf < 4; ++nf)
    vv[nf] = ld1<BF16>(vvec, nb * 128 + wc * 64 + nf * 16 + col);

#pragma unroll
  for (int mf = 0; mf < 2; ++mf) {
    const int row0 = wr * 32 + mf * 16 + quad * 4;
    const int r0 = rbase + row0;
    const int bidx = r0 >> 8;
    const int l0 = r0 & 255;
    const float* ebase = dense_ent + bidx * A_ + 2 * l0 + (nb >> 1);
    float e0 = ebase[0], e1 = ebase[2], e2 = ebase[4], e3 = ebase[6];
    float s0 = 0.f, s1 = 0.f, s2 = 0.f, s3 = 0.f;
#pragma unroll
    for (int nf = 0; nf < 4; ++nf) {
      float vn = vv[nf];
      s0 += tanhf(acc[mf][nf][0] + e0) * vn;
      s1 += tanhf(acc[mf][nf][1] + e1) * vn;
      s2 += tanhf(acc[mf][nf][2] + e2) * vn;
      s3 += tanhf(acc[mf][nf][3] + e3) * vn;
    }
    s0 += __shfl_xor(s0, 1); s0 += __shfl_xor(s0, 2); s0 += __shfl_xor(s0, 4); s0 += __shfl_xor(s0, 8);
    s1 += __shfl_xor(s1, 1); s1 += __shfl_xor(s1, 2); s1 += __shfl_xor(s1, 4); s1 += __shfl_xor(s1, 8);
    s2 += __shfl_xor(s2, 1); s2 += __shfl_xor(s2, 2); s2 += __shfl_xor(s2, 4); s2 += __shfl_xor(s2, 8);
    s3 += __shfl_xor(s3, 1); s3 += __shfl_xor(s3, 2); s3 += __shfl_xor(s3, 4); s3 += __shfl_xor(s3, 8);
    if (col == 0) {
      vu_s[wave][row0 + 0] = s0;
      vu_s[wave][row0 + 1] = s1;
      vu_s[wave][row0 + 2] = s2;
      vu_s[wave][row0 + 3] = s3;
    }
  }
  __syncthreads();
  if (tid < 64) {
    // waves (wrr*2) and (wrr*2+1) hold the two n-halves of row tid
    const int wrr = tid >> 5;
    float s = vu_s[wrr * 2][tid] + vu_s[wrr * 2 + 1][tid];
    vu_part[(size_t)nb * (B_ * L_) + rbase + tid] = s;
  }
}

// ---------------------------------------------------------------------------
// Kernel 5: per-b softmax over L, then z[b,h] = sum_l alpha[l] * wh[b,l,h]
// grid 256 = b*4 + hq. Sums the four n-partials of vu. 8-deep unroll.
// ---------------------------------------------------------------------------
template <bool BF16>
__global__ __launch_bounds__(256) void softmax_z(const void* __restrict__ wh,
                                                 const float* __restrict__ vu_part,
                                                 void* __restrict__ out) {
  const int b = blockIdx.x >> 2;
  const int hq = blockIdx.x & 3;
  const int tid = threadIdx.x;
  __shared__ float alpha[256];
  __shared__ float red[256];

  float x = 0.f;
#pragma unroll
  for (int p = 0; p < 4; ++p) x += vu_part[(size_t)p * (B_ * L_) + b * L_ + tid];
  red[tid] = x;
  __syncthreads();
  for (int s = 128; s > 0; s >>= 1) {
    if (tid < s) red[tid] = fmaxf(red[tid], red[tid + s]);
    __syncthreads();
  }
  float m = red[0];
  __syncthreads();
  float e = __expf(x - m);
  red[tid] = e;
  __syncthreads();
  for (int s = 128; s > 0; s >>= 1) {
    if (tid < s) red[tid] += red[tid + s];
    __syncthreads();
  }
  alpha[tid] = e / red[0];
  __syncthreads();

  const int h = hq * 256 + tid;
  const size_t base = (size_t)b * L_ * H_ + h;
  float a0 = 0.f, a1 = 0.f, a2 = 0.f, a3 = 0.f;
  float a4 = 0.f, a5 = 0.f, a6 = 0.f, a7 = 0.f;
  for (int l = 0; l < 256; l += 8) {
    a0 += alpha[l + 0] * ld1<BF16>(wh, base + (size_t)(l + 0) * H_);
    a1 += alpha[l + 1] * ld1<BF16>(wh, base + (size_t)(l + 1) * H_);
    a2 += alpha[l + 2] * ld1<BF16>(wh, base + (size_t)(l + 2) * H_);
    a3 += alpha[l + 3] * ld1<BF16>(wh, base + (size_t)(l + 3) * H_);
    a4 += alpha[l + 4] * ld1<BF16>(wh, base + (size_t)(l + 4) * H_);
    a5 += alpha[l + 5] * ld1<BF16>(wh, base + (size_t)(l + 5) * H_);
    a6 += alpha[l + 6] * ld1<BF16>(wh, base + (size_t)(l + 6) * H_);
    a7 += alpha[l + 7] * ld1<BF16>(wh, base + (size_t)(l + 7) * H_);
  }
  float z = ((a0 + a1) + (a2 + a3)) + ((a4 + a5) + (a6 + a7));
  if (BF16) ((ushort*)out)[b * H_ + h] = f2bf_rne(z);
  else ((float*)out)[b * H_ + h] = z;
}

// ---------------------------------------------------------------------------
extern "C" void kernel_launch(void* const* d_in, const int* in_sizes, int n_in,
                              void* d_out, int out_size, void* d_ws, size_t ws_size,
                              hipStream_t stream) {
  const void* wh   = d_in[0];
  const void* pe1  = d_in[1];
  const void* pe2  = d_in[2];
  const int*  e1e  = (const int*)d_in[3];
  const int*  e2e  = (const int*)d_in[4];
  const void* temb = d_in[5];
  const void* wpos = d_in[6];
  const void* went = d_in[7];
  const void* vvec = d_in[8];

  const bool bf16 = (in_sizes[0] == (int)(B_ * L_ * H_ * 2));

  char* ws = (char*)d_ws;
  ushort* WTs      = (ushort*)ws;                  // 1,179,648 B
  float* dense_ent = (float*)(ws + 1179648);       // 131,072 B
  float* vu_part   = (float*)(ws + 1310720);       // 262,144 B (aliases EF head;
  float* EF        = (float*)(ws + 1310720);       //  EF dead before fused runs)
  float* part      = (float*)(ws + 2359296);       // 4,194,304 B

  if (bf16) {
    prep_k<true ><<<dim3(640), dim3(256), 0, stream>>>(wpos, WTs, wh, e1e, e2e, temb, EF);
    ent_gemm<true ><<<dim3(256), dim3(256), 0, stream>>>(EF, went, part);
    ent_reduce<<<dim3(128), dim3(256), 0, stream>>>(part, dense_ent);
    fused_gemm_vu<true ><<<dim3(1024), dim3(256), 0, stream>>>(wh, pe1, pe2, WTs, dense_ent, vvec, vu_part);
    softmax_z<true ><<<dim3(256), dim3(256), 0, stream>>>(wh, vu_part, d_out);
  } else {
    prep_k<false><<<dim3(640), dim3(256), 0, stream>>>(wpos, WTs, wh, e1e, e2e, temb, EF);
    ent_gemm<false><<<dim3(256), dim3(256), 0, stream>>>(EF, went, part);
    ent_reduce<<<dim3(128), dim3(256), 0, stream>>>(part, dense_ent);
    fused_gemm_vu<false><<<dim3(1024), dim3(256), 0, stream>>>(wh, pe1, pe2, WTs, dense_ent, vvec, vu_part);
    softmax_z<false><<<dim3(256), dim3(256), 0, stream>>>(wh, vu_part, d_out);
  }
}